// Round 7
// baseline (203.419 us; speedup 1.0000x reference)
//
#include <hip/hip_runtime.h>

#define SEQ 2048
#define NB 4
#define NH 12
#define DHEAD 64
#define DMODEL 768
#define D3 2304
#define MTOT 8192
// attention scale folded with log2(e): exp(x*0.125) == exp2(x*0.125*log2e)
#define QSCALE 0.18033688011112042f

typedef float f4v __attribute__((ext_vector_type(4)));
typedef float fl4 __attribute__((ext_vector_type(4)));
typedef short s8v __attribute__((ext_vector_type(8)));
typedef __bf16 b8v __attribute__((ext_vector_type(8)));
typedef unsigned int ui4 __attribute__((ext_vector_type(4)));
typedef unsigned int ui2 __attribute__((ext_vector_type(2)));
typedef unsigned short us4 __attribute__((ext_vector_type(4)));

// async global->LDS, 16B per lane. LDS dest must be wave-uniform base + lane*16.
#define GLDS16(g, l)                                                            \
  __builtin_amdgcn_global_load_lds(                                             \
      (const __attribute__((address_space(1))) void*)(g),                       \
      (__attribute__((address_space(3))) void*)(l), 16, 0, 0)

// raw v_exp_f32. Safe here: |arg| <~ 12, far from the edges the ocml wrapper pads.
__device__ inline float fast_exp2(float x) {
#if __has_builtin(__builtin_amdgcn_exp2f)
  return __builtin_amdgcn_exp2f(x);
#else
  float r;
  asm("v_exp_f32 %0, %1" : "=v"(r) : "v"(x));
  return r;
#endif
}

// --- MFMA dispatch: tolerate either builtin signature (short8 or bf16x8) ---
template <typename T>
__device__ inline auto mfma_try(T a, T b, f4v c, int)
    -> decltype(__builtin_amdgcn_mfma_f32_16x16x32_bf16(a, b, c, 0, 0, 0)) {
  return __builtin_amdgcn_mfma_f32_16x16x32_bf16(a, b, c, 0, 0, 0);
}
template <typename T>
__device__ inline f4v mfma_try(T a, T b, f4v c, long) {
  return __builtin_amdgcn_mfma_f32_16x16x32_bf16(
      __builtin_bit_cast(b8v, a), __builtin_bit_cast(b8v, b), c, 0, 0, 0);
}
__device__ inline f4v mfma16(s8v a, s8v b, f4v c) { return mfma_try(a, b, c, 0); }

__device__ inline unsigned short f2bf(float f) {
  union { float f; unsigned u; } v; v.f = f;
  unsigned r = v.u + 0x7FFFu + ((v.u >> 16) & 1u);
  return (unsigned short)(r >> 16);
}

// pack two fp32 -> one dword of 2 bf16 (round-half-up == RNE here).
__device__ inline unsigned pack2(float a, float b) {
  unsigned ua = __builtin_bit_cast(unsigned, a) + 0x8000u;
  unsigned ub = __builtin_bit_cast(unsigned, b) + 0x8000u;
  return __builtin_amdgcn_perm(ub, ua, 0x07060302u);  // [ua.hi16 | ub.hi16<<16]
}

// single-instruction RNE pack: a -> low16, b -> high16. Bit-identical to pack2
// (both are round-to-nearest-even on finite positive values); 1 op vs 3.
__device__ inline unsigned cvtpk2(float a, float b) {
  unsigned r;
  asm("v_cvt_pk_bf16_f32 %0, %1, %2" : "=v"(r) : "v"(a), "v"(b));
  return r;
}

// ---------------- fused fp32 -> bf16 convert for x, qkv_w, proj_w -------------
#define NX4 1572864   // 6291456/4
#define NW14 442368   // 1769472/4
#define NW24 147456   // 589824/4
__global__ void k_cvt(const float* __restrict__ x, const float* __restrict__ w1,
                      const float* __restrict__ w2, unsigned short* __restrict__ ox,
                      unsigned short* __restrict__ o1, unsigned short* __restrict__ o2) {
  int i = blockIdx.x * 256 + threadIdx.x;
  const float* src;
  unsigned short* dst;
  int off;
  if (i < NX4) { src = x; dst = ox; off = i; }
  else if (i < NX4 + NW14) { src = w1; dst = o1; off = i - NX4; }
  else if (i < NX4 + NW14 + NW24) { src = w2; dst = o2; off = i - NX4 - NW14; }
  else return;
  fl4 f = ((const fl4*)src)[off];
  us4 o;
  o[0] = f2bf(f[0]); o[1] = f2bf(f[1]); o[2] = f2bf(f[2]); o[3] = f2bf(f[3]);
  ((us4*)dst)[off] = o;
}

// ---------------- fused QKV GEMM, one launch ----------------------------------
// R8 config (best measured): 1536 blocks = 6/CU even; V path 128x64.
// XCD swizzle: 1536 = 8 XCDs x 192, 192 = 8 token-tiles x (12 QK + 12 V).
// Each XCD owns 8 contiguous token-tiles (1.6 MB of x); W stays L2-resident.
__global__ __launch_bounds__(256, 3) void k_qkv(
    const unsigned short* __restrict__ xb,   // [8192][768] bf16
    const unsigned short* __restrict__ wb,   // [2304][768] bf16
    const float* __restrict__ qkv_b,
    unsigned short* __restrict__ outQ,
    unsigned short* __restrict__ outK,
    unsigned short* __restrict__ outV) {
  __shared__ unsigned short As[128 * 64];
  __shared__ unsigned short Bs[128 * 64];
  const int tid = threadIdx.x;
  const int lane = tid & 63;
  const int wave = tid >> 6;
  const int wr = wave >> 1, wc = wave & 1;
  const int lr = lane & 15, lq = lane >> 4;
  const int srow = wave * 8 + (lane >> 3);
  const int scol = ((lane & 7) ^ ((lane >> 3) & 7)) * 8;
  const int swz = (lr & 7);

  // XCD swizzle: assume XCD = blockIdx.x % 8 (round-robin dispatch).
  const int bid = blockIdx.x;
  const int xcd = bid & 7;
  const int cc = bid >> 3;                 // 0..191 within this XCD
  const int tokTile = xcd * 8 + cc / 24;   // 0..63 (128 tokens each)
  const int rsel = cc % 24;                // 0..11 -> QK, 12..23 -> V

  if (rsel < 12) {
    // ------------------- QK path: 128(feat) x 128(tok) -------------------
    const int rowBase = rsel * 128;        // feature 0..1535
    const int colBase = tokTile * 128;     // token
    f4v acc[4][4];
#pragma unroll
    for (int i = 0; i < 4; ++i)
#pragma unroll
      for (int j = 0; j < 4; ++j) acc[i][j] = f4v{0.f, 0.f, 0.f, 0.f};

    const unsigned short* Ag0 = wb + (long)(rowBase + srow) * DMODEL + scol;
    const unsigned short* Bg0 = xb + (long)(colBase + srow) * DMODEL + scol;
    unsigned short* Al0 = &As[srow * 64 + (lane & 7) * 8];
    unsigned short* Bl0 = &Bs[srow * 64 + (lane & 7) * 8];

    for (int kt = 0; kt < DMODEL / 64; ++kt) {
#pragma unroll
      for (int p = 0; p < 4; ++p) {
        GLDS16(Ag0 + kt * 64 + p * 32 * DMODEL, Al0 + p * 32 * 64);
        GLDS16(Bg0 + kt * 64 + p * 32 * DMODEL, Bl0 + p * 32 * 64);
      }
      __syncthreads();
#pragma unroll
      for (int ks = 0; ks < 2; ++ks) {
        s8v af[4], bf[4];
#pragma unroll
        for (int i = 0; i < 4; ++i)
          af[i] = *(const s8v*)&As[(wr * 64 + i * 16 + lr) * 64 + ((ks * 4 + lq) ^ swz) * 8];
#pragma unroll
        for (int j = 0; j < 4; ++j)
          bf[j] = *(const s8v*)&Bs[(wc * 64 + j * 16 + lr) * 64 + ((ks * 4 + lq) ^ swz) * 8];
#pragma unroll
        for (int i = 0; i < 4; ++i)
#pragma unroll
          for (int j = 0; j < 4; ++j) acc[i][j] = mfma16(af[i], bf[j], acc[i][j]);
      }
      __syncthreads();
    }

    const int fw = rowBase + wr * 64;
    fl4 bv[4];
#pragma unroll
    for (int i = 0; i < 4; ++i) bv[i] = *(const fl4*)&qkv_b[fw + i * 16 + lq * 4];
    const int isQ = fw < DMODEL;
    const int h = (fw >> 6) % NH;
    unsigned short* outQK = (unsigned short*)(isQ ? outQ : outK);
    const float scl = isQ ? QSCALE : 1.0f;
#pragma unroll
    for (int j = 0; j < 4; ++j) {
      const int ng = colBase + wc * 64 + j * 16 + lr;   // global token
      const int b = ng >> 11, nn = ng & 2047;
#pragma unroll
      for (int i = 0; i < 4; ++i) {
        float v0 = (acc[i][j][0] + bv[i][0]) * scl, v1 = (acc[i][j][1] + bv[i][1]) * scl;
        float v2 = (acc[i][j][2] + bv[i][2]) * scl, v3 = (acc[i][j][3] + bv[i][3]) * scl;
        *(ui2*)(outQK + (long)(((b * NH + h) * SEQ) + nn) * DHEAD + (i * 16 + lq * 4)) =
            ui2{pack2(v0, v1), pack2(v2, v3)};
      }
    }
  } else {
    // ------------------- V path: 128(tok) x 64(feat) -------------------
    const int rowBase = tokTile * 128;         // token
    const int colBase = (rsel - 12) * 64;      // V feature
    f4v acc[4][2];
#pragma unroll
    for (int i = 0; i < 4; ++i)
#pragma unroll
      for (int j = 0; j < 2; ++j) acc[i][j] = f4v{0.f, 0.f, 0.f, 0.f};

    const unsigned short* Ag0 = xb + (long)(rowBase + srow) * DMODEL + scol;
    const unsigned short* Bg0 =
        wb + (long)(2 * DMODEL + colBase + srow) * DMODEL + scol;
    unsigned short* Al0 = &As[srow * 64 + (lane & 7) * 8];
    unsigned short* Bl0 = &Bs[srow * 64 + (lane & 7) * 8];

    for (int kt = 0; kt < DMODEL / 64; ++kt) {
#pragma unroll
      for (int p = 0; p < 4; ++p)
        GLDS16(Ag0 + kt * 64 + p * 32 * DMODEL, Al0 + p * 32 * 64);
#pragma unroll
      for (int p = 0; p < 2; ++p)
        GLDS16(Bg0 + kt * 64 + p * 32 * DMODEL, Bl0 + p * 32 * 64);
      __syncthreads();
#pragma unroll
      for (int ks = 0; ks < 2; ++ks) {
        s8v af[4], bf[2];
#pragma unroll
        for (int i = 0; i < 4; ++i)
          af[i] = *(const s8v*)&As[(wr * 64 + i * 16 + lr) * 64 + ((ks * 4 + lq) ^ swz) * 8];
#pragma unroll
        for (int j = 0; j < 2; ++j)
          bf[j] = *(const s8v*)&Bs[(wc * 32 + j * 16 + lr) * 64 + ((ks * 4 + lq) ^ swz) * 8];
#pragma unroll
        for (int i = 0; i < 4; ++i)
#pragma unroll
          for (int j = 0; j < 2; ++j) acc[i][j] = mfma16(af[i], bf[j], acc[i][j]);
      }
      __syncthreads();
    }

#pragma unroll
    for (int j = 0; j < 2; ++j) {
      const int col = colBase + wc * 32 + j * 16 + lr;  // V feature 0..767
      const float bvs = qkv_b[2 * DMODEL + col];
      const int h = col >> 6, hd = col & 63;
#pragma unroll
      for (int i = 0; i < 4; ++i) {
        const int row = rowBase + wr * 64 + i * 16 + lq * 4;  // token
        const int b = row >> 11, n = row & 2047;
        const int bq = (n >> 2) & 7;
        const int np = (n & ~31) + ((bq & 3) << 3) + ((bq >> 2) << 2);  // slot perm
        float v0 = acc[i][j][0] + bvs, v1 = acc[i][j][1] + bvs;
        float v2 = acc[i][j][2] + bvs, v3 = acc[i][j][3] + bvs;
        *(ui2*)&outV[(long)(((b * NH + h) * DHEAD) + hd) * SEQ + np] =
            ui2{pack2(v0, v1), pack2(v2, v3)};
      }
    }
  }
}

// ---------------- proj GEMM: 128(feat) x 64(tok) --------------------------
// XCD swizzle. 768 blocks = 8 XCDs x 96 = 16 token-tiles x 6 feature-tiles
// per XCD: Wp (1.2 MB) + token chunk (1.6 MB) stay L2-resident.
__global__ __launch_bounds__(256, 3) void k_proj(
    const unsigned short* __restrict__ Wp,   // [768][768] bf16
    const unsigned short* __restrict__ Xt,   // [8192][768] bf16 (attn out)
    const float* __restrict__ bias,
    float* __restrict__ outF) {
  __shared__ unsigned short As[128 * 64];
  __shared__ unsigned short Bs[64 * 64];
  const int tid = threadIdx.x;
  const int lane = tid & 63;
  const int wave = tid >> 6;
  const int wr = wave >> 1, wc = wave & 1;
  const int lr = lane & 15, lq = lane >> 4;
  const int srow = wave * 8 + (lane >> 3);
  const int scol = ((lane & 7) ^ ((lane >> 3) & 7)) * 8;
  const int swz = (lr & 7);

  const int bid = blockIdx.x;
  const int xcd = bid & 7;
  const int cc = bid >> 3;                 // 0..95
  const int tokTile = xcd * 16 + cc / 6;   // 0..127 (64 tokens each)
  const int rowBase = (cc % 6) * 128;      // out-feature
  const int colBase = tokTile * 64;        // token

  f4v acc[4][2];
#pragma unroll
  for (int i = 0; i < 4; ++i)
#pragma unroll
    for (int j = 0; j < 2; ++j) acc[i][j] = f4v{0.f, 0.f, 0.f, 0.f};

  const unsigned short* Ag0 = Wp + (long)(rowBase + srow) * DMODEL + scol;
  const unsigned short* Bg0 = Xt + (long)(colBase + srow) * DMODEL + scol;
  unsigned short* Al0 = &As[srow * 64 + (lane & 7) * 8];
  unsigned short* Bl0 = &Bs[srow * 64 + (lane & 7) * 8];

  for (int kt = 0; kt < DMODEL / 64; ++kt) {
#pragma unroll
    for (int p = 0; p < 4; ++p)
      GLDS16(Ag0 + kt * 64 + p * 32 * DMODEL, Al0 + p * 32 * 64);
#pragma unroll
    for (int p = 0; p < 2; ++p)
      GLDS16(Bg0 + kt * 64 + p * 32 * DMODEL, Bl0 + p * 32 * 64);
    __syncthreads();
#pragma unroll
    for (int ks = 0; ks < 2; ++ks) {
      s8v af[4], bf[2];
#pragma unroll
      for (int i = 0; i < 4; ++i)
        af[i] = *(const s8v*)&As[(wr * 64 + i * 16 + lr) * 64 + ((ks * 4 + lq) ^ swz) * 8];
#pragma unroll
      for (int j = 0; j < 2; ++j)
        bf[j] = *(const s8v*)&Bs[(wc * 32 + j * 16 + lr) * 64 + ((ks * 4 + lq) ^ swz) * 8];
#pragma unroll
      for (int i = 0; i < 4; ++i)
#pragma unroll
        for (int j = 0; j < 2; ++j) acc[i][j] = mfma16(af[i], bf[j], acc[i][j]);
    }
    __syncthreads();
  }

  const int fw = rowBase + wr * 64;
  fl4 bv[4];
#pragma unroll
  for (int i = 0; i < 4; ++i) bv[i] = *(const fl4*)&bias[fw + i * 16 + lq * 4];
#pragma unroll
  for (int j = 0; j < 2; ++j) {
    const int ng = colBase + wc * 32 + j * 16 + lr;   // token
#pragma unroll
    for (int i = 0; i < 4; ++i) {
      float v0 = acc[i][j][0] + bv[i][0], v1 = acc[i][j][1] + bv[i][1];
      float v2 = acc[i][j][2] + bv[i][2], v3 = acc[i][j][3] + bv[i][3];
      *(fl4*)&outF[(long)ng * DMODEL + fw + i * 16 + lq * 4] = fl4{v0, v1, v2, v3};
    }
  }
}

// ---------------- Flash attention -- R13: R8 + cvt_pk exp-phase shrink --------
// R8 exact (61.4us best: ones-MFMA row-sum, setprio, K-dbuf, issue-early,
// 2 barriers/tile). Single delta: exp-phase pack2 (3 VALU ops) replaced by
// v_cvt_pk_bf16_f32 (1 op, same RNE rounding -> bit-identical). R12 measured
// +64 VALU ops on this phase = +6us (critical convoy path); this removes 64.
__global__ __launch_bounds__(256, 3) void k_attn(
    const unsigned short* __restrict__ Q,   // [B*H, N, 64] bf16, prescaled QSCALE
    const unsigned short* __restrict__ Kg,  // [B*H, N, 64] bf16
    const unsigned short* __restrict__ Vt,  // [B*H, 64, N] bf16, slot-permuted
    unsigned short* __restrict__ Ob) {      // [B, N, 768] bf16
  __shared__ unsigned short Ks[2 * 128 * 64];   // double-buffered K
  __shared__ unsigned short Vs[64 * 128];
  const int tid = threadIdx.x;
  const int lane = tid & 63;
  const int wave = tid >> 6;
  const int lr = lane & 15;
  const int lq = lane >> 4;

  const int bid = blockIdx.x;
  const int xcd = bid & 7;
  const int cc = bid >> 3;                // 0..95
  const int bh = xcd * 6 + cc / 16;       // 0..47
  const int q0 = (cc & 15) * 128;

  const int b = bh / NH, h = bh % NH;
  const unsigned short* Qb = Q + (long)bh * SEQ * DHEAD;
  const unsigned short* Kb = Kg + (long)bh * SEQ * DHEAD;
  const unsigned short* Vb = Vt + (long)bh * DHEAD * SEQ;

  s8v qf[2][2];
#pragma unroll
  for (int i = 0; i < 2; ++i)
#pragma unroll
    for (int ss = 0; ss < 2; ++ss)
      qf[i][ss] = *(const s8v*)(Qb + (q0 + wave * 32 + i * 16 + lr) * DHEAD + ss * 32 + lq * 8);

  f4v o[2][4];
  f4v la[2] = {f4v{0.f, 0.f, 0.f, 0.f}, f4v{0.f, 0.f, 0.f, 0.f}};
  const f4v zc = f4v{0.f, 0.f, 0.f, 0.f};
  const s8v ones = {0x3F80, 0x3F80, 0x3F80, 0x3F80, 0x3F80, 0x3F80, 0x3F80, 0x3F80};
#pragma unroll
  for (int i = 0; i < 2; ++i)
#pragma unroll
    for (int jo = 0; jo < 4; ++jo) o[i][jo] = f4v{0.f, 0.f, 0.f, 0.f};

  const int srow = wave * 8 + (lane >> 3);
  const int scol = ((lane & 7) ^ ((lane >> 3) & 7)) * 8;
  const unsigned short* Kg0 = Kb + (long)srow * DHEAD + scol;
  const int klBase = srow * 64 + (lane & 7) * 8;  // elem offset inside one K buffer
  const int swz = (lr & 7);
  const int vdrow = wave * 4 + (lane >> 4);
  const int vchunk = (lane & 15) ^ vdrow;
  const unsigned short* Vg0 = Vb + (long)vdrow * SEQ + vchunk * 8;
  unsigned short* Vl0 = &Vs[vdrow * 128 + (lane & 15) * 8];

  // prologue: stage K(0) into buffer 0 (only tile whose latency is exposed)
#pragma unroll
  for (int p = 0; p < 4; ++p)
    GLDS16(Kg0 + (long)(p * 32) * DHEAD, &Ks[klBase] + p * 32 * 64);
  __syncthreads();

  int cur = 0;
  for (int kt = 0; kt < SEQ / 128; ++kt) {
    // 1. issue-early async staging: V(kt) -> Vs, K(kt+1) -> other K buffer
#pragma unroll
    for (int p = 0; p < 4; ++p)
      GLDS16(Vg0 + (long)(p * 16) * SEQ + kt * 128, Vl0 + p * 16 * 128);
    if (kt + 1 < SEQ / 128) {
#pragma unroll
      for (int p = 0; p < 4; ++p)
        GLDS16(Kg0 + (long)((kt + 1) * 128 + p * 32) * DHEAD,
               &Ks[(cur ^ 1) * (128 * 64) + klBase] + p * 32 * 64);
    }

    // 2. QK from current K buffer (staged last tile) -- covers staging latency
    const unsigned short* Kc = &Ks[cur * (128 * 64)];
    f4v s[2][8];
    __builtin_amdgcn_s_setprio(1);
#pragma unroll
    for (int t = 0; t < 8; ++t) {
      s8v kf0 = *(const s8v*)&Kc[(t * 16 + lr) * 64 + ((0 * 4 + lq) ^ swz) * 8];
      s8v kf1 = *(const s8v*)&Kc[(t * 16 + lr) * 64 + ((1 * 4 + lq) ^ swz) * 8];
      s[0][t] = mfma16(kf0, qf[0][0], zc);
      s[1][t] = mfma16(kf0, qf[1][0], zc);
      s[0][t] = mfma16(kf1, qf[0][1], s[0][t]);
      s[1][t] = mfma16(kf1, qf[1][1], s[1][t]);
    }
    __builtin_amdgcn_s_setprio(0);

    // exp + single-op RNE pack (was pack2 = 3 ops; cvt_pk is bit-identical)
    unsigned pk[2][8][2];
#pragma unroll
    for (int i = 0; i < 2; ++i)
#pragma unroll
      for (int t = 0; t < 8; ++t) {
        float p0 = fast_exp2(s[i][t][0]);
        float p1 = fast_exp2(s[i][t][1]);
        float p2 = fast_exp2(s[i][t][2]);
        float p3 = fast_exp2(s[i][t][3]);
        pk[i][t][0] = cvtpk2(p0, p1);
        pk[i][t][1] = cvtpk2(p2, p3);
      }

    // 3. drain V(kt) + K(kt+1); all waves done reading Kc
    __syncthreads();

    // 4. PV from Vs (row-sum via ones-MFMA: free on the underused MFMA pipe)
    __builtin_amdgcn_s_setprio(1);
#pragma unroll
    for (int ss = 0; ss < 4; ++ss) {
      s8v vf[4];
#pragma unroll
      for (int jo = 0; jo < 4; ++jo)
        vf[jo] = *(const s8v*)&Vs[(jo * 16 + lr) * 128 + ((ss * 4 + lq) ^ lr) * 8];
#pragma unroll
      for (int i = 0; i < 2; ++i) {
        s8v pf = __builtin_bit_cast(
            s8v, ui4{pk[i][2 * ss][0], pk[i][2 * ss][1], pk[i][2 * ss + 1][0], pk[i][2 * ss + 1][1]});
        la[i] = mfma16(ones, pf, la[i]);
#pragma unroll
        for (int jo = 0; jo < 4; ++jo) o[i][jo] = mfma16(vf[jo], pf, o[i][jo]);
      }
    }
    __builtin_amdgcn_s_setprio(0);

    // 5. all waves done reading Vs (no outstanding vmem here -> cheap barrier)
    __syncthreads();
    cur ^= 1;
  }

  float linv[2];
  linv[0] = 1.0f / la[0][0];
  linv[1] = 1.0f / la[1][0];

#pragma unroll
  for (int i = 0; i < 2; ++i) {
    const long nrow = (long)(b * SEQ + q0 + wave * 32 + i * 16 + lr) * DMODEL;
#pragma unroll
    for (int jo = 0; jo < 4; ++jo) {
      float v0 = o[i][jo][0] * linv[i];
      float v1 = o[i][jo][1] * linv[i];
      float v2 = o[i][jo][2] * linv[i];
      float v3 = o[i][jo][3] * linv[i];
      *(ui2*)(Ob + nrow + h * DHEAD + jo * 16 + lq * 4) = ui2{pack2(v0, v1), pack2(v2, v3)};
    }
  }
}

extern "C" void kernel_launch(void* const* d_in, const int* in_sizes, int n_in,
                              void* d_out, int out_size, void* d_ws, size_t ws_size,
                              hipStream_t stream) {
  (void)in_sizes; (void)n_in; (void)out_size; (void)ws_size;
  const float* x = (const float*)d_in[0];
  const float* qkv_w = (const float*)d_in[1];
  const float* qkv_b = (const float*)d_in[2];
  const float* proj_w = (const float*)d_in[3];
  const float* proj_b = (const float*)d_in[4];
  float* out = (float*)d_out;

  unsigned short* ws = (unsigned short*)d_ws;
  unsigned short* xb = ws;                    // 6291456 elts
  unsigned short* wqkvb = xb + 6291456;       // 1769472
  unsigned short* wprjb = wqkvb + 1769472;    // 589824
  unsigned short* qb = wprjb + 589824;        // 6291456
  unsigned short* kb = qb + 6291456;          // 6291456
  unsigned short* vtb = kb + 6291456;         // 6291456
  unsigned short* aob = vtb + 6291456;        // 6291456  (~68 MB total)

  k_cvt<<<(NX4 + NW14 + NW24 + 255) / 256, 256, 0, stream>>>(
      x, qkv_w, proj_w, xb, wqkvb, wprjb);

  k_qkv<<<1536, 256, 0, stream>>>(xb, wqkvb, qkv_b, qb, kb, vtb);
  k_attn<<<768, 256, 0, stream>>>(qb, kb, vtb, aob);
  k_proj<<<768, 256, 0, stream>>>(wprjb, aob, proj_b, out);
}

// Round 8
// 195.297 us; speedup vs baseline: 1.0416x; 1.0416x over previous
//
#include <hip/hip_runtime.h>

#define SEQ 2048
#define NB 4
#define NH 12
#define DHEAD 64
#define DMODEL 768
#define D3 2304
#define MTOT 8192
// attention scale folded with log2(e): exp(x*0.125) == exp2(x*0.125*log2e)
#define QSCALE 0.18033688011112042f

typedef float f4v __attribute__((ext_vector_type(4)));
typedef float fl4 __attribute__((ext_vector_type(4)));
typedef short s8v __attribute__((ext_vector_type(8)));
typedef __bf16 b8v __attribute__((ext_vector_type(8)));
typedef unsigned int ui4 __attribute__((ext_vector_type(4)));
typedef unsigned int ui2 __attribute__((ext_vector_type(2)));
typedef unsigned short us4 __attribute__((ext_vector_type(4)));

// async global->LDS, 16B per lane. LDS dest must be wave-uniform base + lane*16.
#define GLDS16(g, l)                                                            \
  __builtin_amdgcn_global_load_lds(                                             \
      (const __attribute__((address_space(1))) void*)(g),                       \
      (__attribute__((address_space(3))) void*)(l), 16, 0, 0)

// raw v_exp_f32. Safe here: |arg| <~ 12, far from the edges the ocml wrapper pads.
__device__ inline float fast_exp2(float x) {
#if __has_builtin(__builtin_amdgcn_exp2f)
  return __builtin_amdgcn_exp2f(x);
#else
  float r;
  asm("v_exp_f32 %0, %1" : "=v"(r) : "v"(x));
  return r;
#endif
}

// --- MFMA dispatch: tolerate either builtin signature (short8 or bf16x8) ---
template <typename T>
__device__ inline auto mfma_try(T a, T b, f4v c, int)
    -> decltype(__builtin_amdgcn_mfma_f32_16x16x32_bf16(a, b, c, 0, 0, 0)) {
  return __builtin_amdgcn_mfma_f32_16x16x32_bf16(a, b, c, 0, 0, 0);
}
template <typename T>
__device__ inline f4v mfma_try(T a, T b, f4v c, long) {
  return __builtin_amdgcn_mfma_f32_16x16x32_bf16(
      __builtin_bit_cast(b8v, a), __builtin_bit_cast(b8v, b), c, 0, 0, 0);
}
__device__ inline f4v mfma16(s8v a, s8v b, f4v c) { return mfma_try(a, b, c, 0); }

__device__ inline unsigned short f2bf(float f) {
  union { float f; unsigned u; } v; v.f = f;
  unsigned r = v.u + 0x7FFFu + ((v.u >> 16) & 1u);
  return (unsigned short)(r >> 16);
}

// pack two fp32 -> one dword of 2 bf16 (round-half-up == RNE here).
__device__ inline unsigned pack2(float a, float b) {
  unsigned ua = __builtin_bit_cast(unsigned, a) + 0x8000u;
  unsigned ub = __builtin_bit_cast(unsigned, b) + 0x8000u;
  return __builtin_amdgcn_perm(ub, ua, 0x07060302u);  // [ua.hi16 | ub.hi16<<16]
}

// single-instruction RNE pack: a -> low16, b -> high16. Bit-identical to pack2
// (verified on-HW in R13: same absmax); 1 op vs 3.
__device__ inline unsigned cvtpk2(float a, float b) {
  unsigned r;
  asm("v_cvt_pk_bf16_f32 %0, %1, %2" : "=v"(r) : "v"(a), "v"(b));
  return r;
}

// ---------------- fused fp32 -> bf16 convert for x, qkv_w, proj_w -------------
#define NX4 1572864   // 6291456/4
#define NW14 442368   // 1769472/4
#define NW24 147456   // 589824/4
__global__ void k_cvt(const float* __restrict__ x, const float* __restrict__ w1,
                      const float* __restrict__ w2, unsigned short* __restrict__ ox,
                      unsigned short* __restrict__ o1, unsigned short* __restrict__ o2) {
  int i = blockIdx.x * 256 + threadIdx.x;
  const float* src;
  unsigned short* dst;
  int off;
  if (i < NX4) { src = x; dst = ox; off = i; }
  else if (i < NX4 + NW14) { src = w1; dst = o1; off = i - NX4; }
  else if (i < NX4 + NW14 + NW24) { src = w2; dst = o2; off = i - NX4 - NW14; }
  else return;
  fl4 f = ((const fl4*)src)[off];
  ui2 o = ui2{cvtpk2(f[0], f[1]), cvtpk2(f[2], f[3])};
  ((ui2*)dst)[off] = o;
}

// ---------------- fused QKV GEMM, one launch ----------------------------------
// R8 config (best measured): 1536 blocks = 6/CU even; V path 128x64.
// XCD swizzle: 1536 = 8 XCDs x 192, 192 = 8 token-tiles x (12 QK + 12 V).
// Each XCD owns 8 contiguous token-tiles (1.6 MB of x); W stays L2-resident.
__global__ __launch_bounds__(256, 3) void k_qkv(
    const unsigned short* __restrict__ xb,   // [8192][768] bf16
    const unsigned short* __restrict__ wb,   // [2304][768] bf16
    const float* __restrict__ qkv_b,
    unsigned short* __restrict__ outQ,
    unsigned short* __restrict__ outK,
    unsigned short* __restrict__ outV) {
  __shared__ unsigned short As[128 * 64];
  __shared__ unsigned short Bs[128 * 64];
  const int tid = threadIdx.x;
  const int lane = tid & 63;
  const int wave = tid >> 6;
  const int wr = wave >> 1, wc = wave & 1;
  const int lr = lane & 15, lq = lane >> 4;
  const int srow = wave * 8 + (lane >> 3);
  const int scol = ((lane & 7) ^ ((lane >> 3) & 7)) * 8;
  const int swz = (lr & 7);

  // XCD swizzle: assume XCD = blockIdx.x % 8 (round-robin dispatch).
  const int bid = blockIdx.x;
  const int xcd = bid & 7;
  const int cc = bid >> 3;                 // 0..191 within this XCD
  const int tokTile = xcd * 8 + cc / 24;   // 0..63 (128 tokens each)
  const int rsel = cc % 24;                // 0..11 -> QK, 12..23 -> V

  if (rsel < 12) {
    // ------------------- QK path: 128(feat) x 128(tok) -------------------
    const int rowBase = rsel * 128;        // feature 0..1535
    const int colBase = tokTile * 128;     // token
    f4v acc[4][4];
#pragma unroll
    for (int i = 0; i < 4; ++i)
#pragma unroll
      for (int j = 0; j < 4; ++j) acc[i][j] = f4v{0.f, 0.f, 0.f, 0.f};

    const unsigned short* Ag0 = wb + (long)(rowBase + srow) * DMODEL + scol;
    const unsigned short* Bg0 = xb + (long)(colBase + srow) * DMODEL + scol;
    unsigned short* Al0 = &As[srow * 64 + (lane & 7) * 8];
    unsigned short* Bl0 = &Bs[srow * 64 + (lane & 7) * 8];

    for (int kt = 0; kt < DMODEL / 64; ++kt) {
#pragma unroll
      for (int p = 0; p < 4; ++p) {
        GLDS16(Ag0 + kt * 64 + p * 32 * DMODEL, Al0 + p * 32 * 64);
        GLDS16(Bg0 + kt * 64 + p * 32 * DMODEL, Bl0 + p * 32 * 64);
      }
      __syncthreads();
#pragma unroll
      for (int ks = 0; ks < 2; ++ks) {
        s8v af[4], bf[4];
#pragma unroll
        for (int i = 0; i < 4; ++i)
          af[i] = *(const s8v*)&As[(wr * 64 + i * 16 + lr) * 64 + ((ks * 4 + lq) ^ swz) * 8];
#pragma unroll
        for (int j = 0; j < 4; ++j)
          bf[j] = *(const s8v*)&Bs[(wc * 64 + j * 16 + lr) * 64 + ((ks * 4 + lq) ^ swz) * 8];
#pragma unroll
        for (int i = 0; i < 4; ++i)
#pragma unroll
          for (int j = 0; j < 4; ++j) acc[i][j] = mfma16(af[i], bf[j], acc[i][j]);
      }
      __syncthreads();
    }

    const int fw = rowBase + wr * 64;
    fl4 bv[4];
#pragma unroll
    for (int i = 0; i < 4; ++i) bv[i] = *(const fl4*)&qkv_b[fw + i * 16 + lq * 4];
    const int isQ = fw < DMODEL;
    const int h = (fw >> 6) % NH;
    unsigned short* outQK = (unsigned short*)(isQ ? outQ : outK);
    const float scl = isQ ? QSCALE : 1.0f;
#pragma unroll
    for (int j = 0; j < 4; ++j) {
      const int ng = colBase + wc * 64 + j * 16 + lr;   // global token
      const int b = ng >> 11, nn = ng & 2047;
#pragma unroll
      for (int i = 0; i < 4; ++i) {
        float v0 = (acc[i][j][0] + bv[i][0]) * scl, v1 = (acc[i][j][1] + bv[i][1]) * scl;
        float v2 = (acc[i][j][2] + bv[i][2]) * scl, v3 = (acc[i][j][3] + bv[i][3]) * scl;
        *(ui2*)(outQK + (long)(((b * NH + h) * SEQ) + nn) * DHEAD + (i * 16 + lq * 4)) =
            ui2{cvtpk2(v0, v1), cvtpk2(v2, v3)};
      }
    }
  } else {
    // ------------------- V path: 128(tok) x 64(feat) -------------------
    const int rowBase = tokTile * 128;         // token
    const int colBase = (rsel - 12) * 64;      // V feature
    f4v acc[4][2];
#pragma unroll
    for (int i = 0; i < 4; ++i)
#pragma unroll
      for (int j = 0; j < 2; ++j) acc[i][j] = f4v{0.f, 0.f, 0.f, 0.f};

    const unsigned short* Ag0 = xb + (long)(rowBase + srow) * DMODEL + scol;
    const unsigned short* Bg0 =
        wb + (long)(2 * DMODEL + colBase + srow) * DMODEL + scol;
    unsigned short* Al0 = &As[srow * 64 + (lane & 7) * 8];
    unsigned short* Bl0 = &Bs[srow * 64 + (lane & 7) * 8];

    for (int kt = 0; kt < DMODEL / 64; ++kt) {
#pragma unroll
      for (int p = 0; p < 4; ++p)
        GLDS16(Ag0 + kt * 64 + p * 32 * DMODEL, Al0 + p * 32 * 64);
#pragma unroll
      for (int p = 0; p < 2; ++p)
        GLDS16(Bg0 + kt * 64 + p * 32 * DMODEL, Bl0 + p * 32 * 64);
      __syncthreads();
#pragma unroll
      for (int ks = 0; ks < 2; ++ks) {
        s8v af[4], bf[2];
#pragma unroll
        for (int i = 0; i < 4; ++i)
          af[i] = *(const s8v*)&As[(wr * 64 + i * 16 + lr) * 64 + ((ks * 4 + lq) ^ swz) * 8];
#pragma unroll
        for (int j = 0; j < 2; ++j)
          bf[j] = *(const s8v*)&Bs[(wc * 32 + j * 16 + lr) * 64 + ((ks * 4 + lq) ^ swz) * 8];
#pragma unroll
        for (int i = 0; i < 4; ++i)
#pragma unroll
          for (int j = 0; j < 2; ++j) acc[i][j] = mfma16(af[i], bf[j], acc[i][j]);
      }
      __syncthreads();
    }

#pragma unroll
    for (int j = 0; j < 2; ++j) {
      const int col = colBase + wc * 32 + j * 16 + lr;  // V feature 0..767
      const float bvs = qkv_b[2 * DMODEL + col];
      const int h = col >> 6, hd = col & 63;
#pragma unroll
      for (int i = 0; i < 4; ++i) {
        const int row = rowBase + wr * 64 + i * 16 + lq * 4;  // token
        const int b = row >> 11, n = row & 2047;
        const int bq = (n >> 2) & 7;
        const int np = (n & ~31) + ((bq & 3) << 3) + ((bq >> 2) << 2);  // slot perm
        float v0 = acc[i][j][0] + bvs, v1 = acc[i][j][1] + bvs;
        float v2 = acc[i][j][2] + bvs, v3 = acc[i][j][3] + bvs;
        *(ui2*)&outV[(long)(((b * NH + h) * DHEAD) + hd) * SEQ + np] =
            ui2{cvtpk2(v0, v1), cvtpk2(v2, v3)};
      }
    }
  }
}

// ---------------- proj GEMM: 128(feat) x 64(tok) --------------------------
// XCD swizzle. 768 blocks = 8 XCDs x 96 = 16 token-tiles x 6 feature-tiles
// per XCD: Wp (1.2 MB) + token chunk (1.6 MB) stay L2-resident.
__global__ __launch_bounds__(256, 3) void k_proj(
    const unsigned short* __restrict__ Wp,   // [768][768] bf16
    const unsigned short* __restrict__ Xt,   // [8192][768] bf16 (attn out)
    const float* __restrict__ bias,
    float* __restrict__ outF) {
  __shared__ unsigned short As[128 * 64];
  __shared__ unsigned short Bs[64 * 64];
  const int tid = threadIdx.x;
  const int lane = tid & 63;
  const int wave = tid >> 6;
  const int wr = wave >> 1, wc = wave & 1;
  const int lr = lane & 15, lq = lane >> 4;
  const int srow = wave * 8 + (lane >> 3);
  const int scol = ((lane & 7) ^ ((lane >> 3) & 7)) * 8;
  const int swz = (lr & 7);

  const int bid = blockIdx.x;
  const int xcd = bid & 7;
  const int cc = bid >> 3;                 // 0..95
  const int tokTile = xcd * 16 + cc / 6;   // 0..127 (64 tokens each)
  const int rowBase = (cc % 6) * 128;      // out-feature
  const int colBase = tokTile * 64;        // token

  f4v acc[4][2];
#pragma unroll
  for (int i = 0; i < 4; ++i)
#pragma unroll
    for (int j = 0; j < 2; ++j) acc[i][j] = f4v{0.f, 0.f, 0.f, 0.f};

  const unsigned short* Ag0 = Wp + (long)(rowBase + srow) * DMODEL + scol;
  const unsigned short* Bg0 = Xt + (long)(colBase + srow) * DMODEL + scol;
  unsigned short* Al0 = &As[srow * 64 + (lane & 7) * 8];
  unsigned short* Bl0 = &Bs[srow * 64 + (lane & 7) * 8];

  for (int kt = 0; kt < DMODEL / 64; ++kt) {
#pragma unroll
    for (int p = 0; p < 4; ++p)
      GLDS16(Ag0 + kt * 64 + p * 32 * DMODEL, Al0 + p * 32 * 64);
#pragma unroll
    for (int p = 0; p < 2; ++p)
      GLDS16(Bg0 + kt * 64 + p * 32 * DMODEL, Bl0 + p * 32 * 64);
    __syncthreads();
#pragma unroll
    for (int ks = 0; ks < 2; ++ks) {
      s8v af[4], bf[2];
#pragma unroll
      for (int i = 0; i < 4; ++i)
        af[i] = *(const s8v*)&As[(wr * 64 + i * 16 + lr) * 64 + ((ks * 4 + lq) ^ swz) * 8];
#pragma unroll
      for (int j = 0; j < 2; ++j)
        bf[j] = *(const s8v*)&Bs[(wc * 32 + j * 16 + lr) * 64 + ((ks * 4 + lq) ^ swz) * 8];
#pragma unroll
      for (int i = 0; i < 4; ++i)
#pragma unroll
        for (int j = 0; j < 2; ++j) acc[i][j] = mfma16(af[i], bf[j], acc[i][j]);
    }
    __syncthreads();
  }

  const int fw = rowBase + wr * 64;
  fl4 bv[4];
#pragma unroll
  for (int i = 0; i < 4; ++i) bv[i] = *(const fl4*)&bias[fw + i * 16 + lq * 4];
#pragma unroll
  for (int j = 0; j < 2; ++j) {
    const int ng = colBase + wc * 32 + j * 16 + lr;   // token
#pragma unroll
    for (int i = 0; i < 4; ++i) {
      float v0 = acc[i][j][0] + bv[i][0], v1 = acc[i][j][1] + bv[i][1];
      float v2 = acc[i][j][2] + bv[i][2], v3 = acc[i][j][3] + bv[i][3];
      *(fl4*)&outF[(long)ng * DMODEL + fw + i * 16 + lq * 4] = fl4{v0, v1, v2, v3};
    }
  }
}

// ---------------- Flash attention -- R14: split-interleaved exp ----------------
// R13 (57.7us) + one delta: exp/cvtpk split -- t=0..3 before barrier 3 (keeps
// V/K drain cover), t=4..5 after ss=0's MFMAs, t=6..7 after ss=1's (issue into
// the 10-MFMA matrix-pipe shadow; consumed 2 ss-groups later -- no serial head).
// Ledger basis: R9/R12 show interleave itself ~neutral-to-positive (-1us), the
// exp-phase op count is the critical-path cost (+-0.06-0.09us/op). setprio kept
// ONLY on pure-MFMA stretches (QK whole; PV per-ss), never over VALU (R9 lesson).
// VGPR crossing barrier: s[t4..7](32) + pk[t0..3](16) -> ~150 peak, <170 cap.
// Spill tripwire: WRITE_SIZE must stay 12288.
__global__ __launch_bounds__(256, 3) void k_attn(
    const unsigned short* __restrict__ Q,   // [B*H, N, 64] bf16, prescaled QSCALE
    const unsigned short* __restrict__ Kg,  // [B*H, N, 64] bf16
    const unsigned short* __restrict__ Vt,  // [B*H, 64, N] bf16, slot-permuted
    unsigned short* __restrict__ Ob) {      // [B, N, 768] bf16
  __shared__ unsigned short Ks[2 * 128 * 64];   // double-buffered K
  __shared__ unsigned short Vs[64 * 128];
  const int tid = threadIdx.x;
  const int lane = tid & 63;
  const int wave = tid >> 6;
  const int lr = lane & 15;
  const int lq = lane >> 4;

  const int bid = blockIdx.x;
  const int xcd = bid & 7;
  const int cc = bid >> 3;                // 0..95
  const int bh = xcd * 6 + cc / 16;       // 0..47
  const int q0 = (cc & 15) * 128;

  const int b = bh / NH, h = bh % NH;
  const unsigned short* Qb = Q + (long)bh * SEQ * DHEAD;
  const unsigned short* Kb = Kg + (long)bh * SEQ * DHEAD;
  const unsigned short* Vb = Vt + (long)bh * DHEAD * SEQ;

  s8v qf[2][2];
#pragma unroll
  for (int i = 0; i < 2; ++i)
#pragma unroll
    for (int ss = 0; ss < 2; ++ss)
      qf[i][ss] = *(const s8v*)(Qb + (q0 + wave * 32 + i * 16 + lr) * DHEAD + ss * 32 + lq * 8);

  f4v o[2][4];
  f4v la[2] = {f4v{0.f, 0.f, 0.f, 0.f}, f4v{0.f, 0.f, 0.f, 0.f}};
  const f4v zc = f4v{0.f, 0.f, 0.f, 0.f};
  const s8v ones = {0x3F80, 0x3F80, 0x3F80, 0x3F80, 0x3F80, 0x3F80, 0x3F80, 0x3F80};
#pragma unroll
  for (int i = 0; i < 2; ++i)
#pragma unroll
    for (int jo = 0; jo < 4; ++jo) o[i][jo] = f4v{0.f, 0.f, 0.f, 0.f};

  const int srow = wave * 8 + (lane >> 3);
  const int scol = ((lane & 7) ^ ((lane >> 3) & 7)) * 8;
  const unsigned short* Kg0 = Kb + (long)srow * DHEAD + scol;
  const int klBase = srow * 64 + (lane & 7) * 8;  // elem offset inside one K buffer
  const int swz = (lr & 7);
  const int vdrow = wave * 4 + (lane >> 4);
  const int vchunk = (lane & 15) ^ vdrow;
  const unsigned short* Vg0 = Vb + (long)vdrow * SEQ + vchunk * 8;
  unsigned short* Vl0 = &Vs[vdrow * 128 + (lane & 15) * 8];

  // prologue: stage K(0) into buffer 0 (only tile whose latency is exposed)
#pragma unroll
  for (int p = 0; p < 4; ++p)
    GLDS16(Kg0 + (long)(p * 32) * DHEAD, &Ks[klBase] + p * 32 * 64);
  __syncthreads();

  int cur = 0;
  for (int kt = 0; kt < SEQ / 128; ++kt) {
    // 1. issue-early async staging: V(kt) -> Vs, K(kt+1) -> other K buffer
#pragma unroll
    for (int p = 0; p < 4; ++p)
      GLDS16(Vg0 + (long)(p * 16) * SEQ + kt * 128, Vl0 + p * 16 * 128);
    if (kt + 1 < SEQ / 128) {
#pragma unroll
      for (int p = 0; p < 4; ++p)
        GLDS16(Kg0 + (long)((kt + 1) * 128 + p * 32) * DHEAD,
               &Ks[(cur ^ 1) * (128 * 64) + klBase] + p * 32 * 64);
    }

    // 2. QK from current K buffer (staged last tile) -- covers staging latency
    const unsigned short* Kc = &Ks[cur * (128 * 64)];
    f4v s[2][8];
    __builtin_amdgcn_s_setprio(1);
#pragma unroll
    for (int t = 0; t < 8; ++t) {
      s8v kf0 = *(const s8v*)&Kc[(t * 16 + lr) * 64 + ((0 * 4 + lq) ^ swz) * 8];
      s8v kf1 = *(const s8v*)&Kc[(t * 16 + lr) * 64 + ((1 * 4 + lq) ^ swz) * 8];
      s[0][t] = mfma16(kf0, qf[0][0], zc);
      s[1][t] = mfma16(kf0, qf[1][0], zc);
      s[0][t] = mfma16(kf1, qf[0][1], s[0][t]);
      s[1][t] = mfma16(kf1, qf[1][1], s[1][t]);
    }
    __builtin_amdgcn_s_setprio(0);

    // exp first half (t=0..3): covers the V/K drain at barrier 3
    unsigned pk[2][8][2];
#pragma unroll
    for (int i = 0; i < 2; ++i)
#pragma unroll
      for (int t = 0; t < 4; ++t) {
        float p0 = fast_exp2(s[i][t][0]);
        float p1 = fast_exp2(s[i][t][1]);
        float p2 = fast_exp2(s[i][t][2]);
        float p3 = fast_exp2(s[i][t][3]);
        pk[i][t][0] = cvtpk2(p0, p1);
        pk[i][t][1] = cvtpk2(p2, p3);
      }

    // 3. drain V(kt) + K(kt+1); all waves done reading Kc
    __syncthreads();

    // 4. PV from Vs; exp second half issues into the MFMA shadow:
    //    after ss=0's MFMAs -> exp(t=4,5); after ss=1's -> exp(t=6,7);
    //    consumed by ss=2/ss=3 (two groups later -> no serial head).
#pragma unroll
    for (int ss = 0; ss < 4; ++ss) {
      s8v vf[4];
#pragma unroll
      for (int jo = 0; jo < 4; ++jo)
        vf[jo] = *(const s8v*)&Vs[(jo * 16 + lr) * 128 + ((ss * 4 + lq) ^ lr) * 8];
      __builtin_amdgcn_s_setprio(1);
#pragma unroll
      for (int i = 0; i < 2; ++i) {
        s8v pf = __builtin_bit_cast(
            s8v, ui4{pk[i][2 * ss][0], pk[i][2 * ss][1], pk[i][2 * ss + 1][0], pk[i][2 * ss + 1][1]});
        la[i] = mfma16(ones, pf, la[i]);
#pragma unroll
        for (int jo = 0; jo < 4; ++jo) o[i][jo] = mfma16(vf[jo], pf, o[i][jo]);
      }
      __builtin_amdgcn_s_setprio(0);
      if (ss < 2) {
#pragma unroll
        for (int i = 0; i < 2; ++i)
#pragma unroll
          for (int t = 4 + 2 * ss; t < 6 + 2 * ss; ++t) {
            float p0 = fast_exp2(s[i][t][0]);
            float p1 = fast_exp2(s[i][t][1]);
            float p2 = fast_exp2(s[i][t][2]);
            float p3 = fast_exp2(s[i][t][3]);
            pk[i][t][0] = cvtpk2(p0, p1);
            pk[i][t][1] = cvtpk2(p2, p3);
          }
      }
    }

    // 5. all waves done reading Vs (no outstanding vmem here -> cheap barrier)
    __syncthreads();
    cur ^= 1;
  }

  float linv[2];
  linv[0] = 1.0f / la[0][0];
  linv[1] = 1.0f / la[1][0];

#pragma unroll
  for (int i = 0; i < 2; ++i) {
    const long nrow = (long)(b * SEQ + q0 + wave * 32 + i * 16 + lr) * DMODEL;
#pragma unroll
    for (int jo = 0; jo < 4; ++jo) {
      float v0 = o[i][jo][0] * linv[i];
      float v1 = o[i][jo][1] * linv[i];
      float v2 = o[i][jo][2] * linv[i];
      float v3 = o[i][jo][3] * linv[i];
      *(ui2*)(Ob + nrow + h * DHEAD + jo * 16 + lq * 4) = ui2{cvtpk2(v0, v1), cvtpk2(v2, v3)};
    }
  }
}

extern "C" void kernel_launch(void* const* d_in, const int* in_sizes, int n_in,
                              void* d_out, int out_size, void* d_ws, size_t ws_size,
                              hipStream_t stream) {
  (void)in_sizes; (void)n_in; (void)out_size; (void)ws_size;
  const float* x = (const float*)d_in[0];
  const float* qkv_w = (const float*)d_in[1];
  const float* qkv_b = (const float*)d_in[2];
  const float* proj_w = (const float*)d_in[3];
  const float* proj_b = (const float*)d_in[4];
  float* out = (float*)d_out;

  unsigned short* ws = (unsigned short*)d_ws;
  unsigned short* xb = ws;                    // 6291456 elts
  unsigned short* wqkvb = xb + 6291456;       // 1769472
  unsigned short* wprjb = wqkvb + 1769472;    // 589824
  unsigned short* qb = wprjb + 589824;        // 6291456
  unsigned short* kb = qb + 6291456;          // 6291456
  unsigned short* vtb = kb + 6291456;         // 6291456
  unsigned short* aob = vtb + 6291456;        // 6291456  (~68 MB total)

  k_cvt<<<(NX4 + NW14 + NW24 + 255) / 256, 256, 0, stream>>>(
      x, qkv_w, proj_w, xb, wqkvb, wprjb);

  k_qkv<<<1536, 256, 0, stream>>>(xb, wqkvb, qkv_b, qb, kb, vtb);
  k_attn<<<768, 256, 0, stream>>>(qb, kb, vtb, aob);
  k_proj<<<768, 256, 0, stream>>>(wprjb, aob, proj_b, out);
}